// Round 14
// baseline (301.302 us; speedup 1.0000x reference)
//
#include <hip/hip_runtime.h>
#include <hip/hip_bf16.h>

#define LN_EPS 1e-5f
#define HB 64          // histogram edge-chunks (power of 2)
#define HSEG 12800     // histogram LDS segment (51.2 KB)
#define NBLK 128       // binning blocks
#define BROWS 64       // rows per dst bucket
#define WPSTRIDE 17408 // 128*136 shorts per packed weight

typedef __attribute__((ext_vector_type(8))) short short8;
typedef __attribute__((ext_vector_type(4))) float f32x4;

// ---- bf16 helpers (bit-level, RNE) ----
__device__ __forceinline__ unsigned short f2bf(float f) {
    unsigned int u = __float_as_uint(f);
    u += 0x7fffu + ((u >> 16) & 1u);
    return (unsigned short)(u >> 16);
}
__device__ __forceinline__ unsigned int pack2bf(float a, float b) {
    return (unsigned int)f2bf(a) | ((unsigned int)f2bf(b) << 16);
}
__device__ __forceinline__ float bflo(unsigned int v) { return __uint_as_float(v << 16); }
__device__ __forceinline__ float bfhi(unsigned int v) { return __uint_as_float(v & 0xffff0000u); }

// ---------------- mega-front: hist + binA + weight-pack + prep (one launch) ----------------
__global__ __launch_bounds__(256) void k_front(const int* __restrict__ src, int* __restrict__ partials,
                                               const int* __restrict__ dst, int* __restrict__ counts,
                                               const float* __restrict__ Wa, const float* __restrict__ Wb,
                                               const float* __restrict__ Wc, const float* __restrict__ Wd,
                                               unsigned short* __restrict__ wpack,
                                               const float* __restrict__ feat, const float* __restrict__ noise,
                                               const int* __restrict__ mask, const float* __restrict__ token,
                                               unsigned short* __restrict__ xs, float* __restrict__ feat_out,
                                               float* __restrict__ mask_out,
                                               int nbuck, int E, int n, int N) {
    __shared__ int h[HSEG];
    int bid = blockIdx.x;
    int tid = threadIdx.x;
    if (bid < 256) {
        int chunk = bid & (HB - 1);
        int seg = bid >> 6;
        int lo = seg * HSEG;
        int len = N - lo;
        if (len > HSEG) len = HSEG;
        if (len <= 0) return;
        for (int i = tid; i < len; i += 256) h[i] = 0;
        __syncthreads();
        int per = (E + HB - 1) / HB;
        int e0 = chunk * per, e1 = min(e0 + per, E);
        for (int e = e0 + tid; e < e1; e += 256) {
            int s = src[e] - lo;
            if ((unsigned)s < (unsigned)len) atomicAdd(&h[s], 1);
        }
        __syncthreads();
        for (int i = tid; i < len; i += 256)
            partials[(size_t)chunk * N + lo + i] = h[i];
        return;
    }
    bid -= 256;
    if (bid < NBLK) {
        for (int i = tid; i < nbuck; i += 256) h[i] = 0;
        __syncthreads();
        int per = (E + NBLK - 1) / NBLK;
        int e0 = bid * per, e1 = min(e0 + per, E);
        for (int e = e0 + tid; e < e1; e += 256) atomicAdd(&h[dst[e] >> 6], 1);
        __syncthreads();
        for (int i = tid; i < nbuck; i += 256) counts[(size_t)i * NBLK + bid] = h[i];
        return;
    }
    bid -= NBLK;
    if (bid < 256) {
        int idx = bid * 256 + tid;
        int wsel = idx >> 14;
        int within = idx & 16383;
        const float* W = wsel == 0 ? Wa : wsel == 1 ? Wb : wsel == 2 ? Wc : Wd;
        int c = within >> 7, kk = within & 127;
        wpack[(size_t)wsel * WPSTRIDE + c * 136 + kk] = f2bf(W[kk * 128 + c]);
        return;
    }
    bid -= 256;
    int i = bid * 256 + tid;
    int total = n * 32;
    if (i >= total) return;
    int row = i >> 5, q = i & 31;
    float4 f = ((const float4*)feat)[i];
    float4 nz = ((const float4*)noise)[i];
    bool m = mask[row] != 0;
    float4 b = f;
    if (m) b = ((const float4*)token)[q];
    uint2 p;
    p.x = pack2bf(b.x + 0.1f * nz.x, b.y + 0.1f * nz.y);
    p.y = pack2bf(b.z + 0.1f * nz.z, b.w + 0.1f * nz.w);
    ((uint2*)xs)[i] = p;
    ((float4*)feat_out)[i] = f;
    if (q == 0) mask_out[row] = m ? 1.0f : 0.0f;
}

// ---------------- mid1: binB1 bucket totals + hist reduce ----------------
__global__ __launch_bounds__(128) void k_mid1(const int* __restrict__ counts, int* __restrict__ tot,
                                              const int* __restrict__ partials, float* __restrict__ doutv,
                                              int nbuck, int N) {
    int t = threadIdx.x;
    int bid = blockIdx.x;
    if (bid < nbuck) {
        __shared__ int sm[128];
        sm[t] = counts[(size_t)bid * NBLK + t];
        __syncthreads();
#pragma unroll
        for (int o = 64; o >= 1; o >>= 1) {
            if (t < o) sm[t] += sm[t + o];
            __syncthreads();
        }
        if (t == 0) tot[bid] = sm[0];
        return;
    }
    int i = (bid - nbuck) * 128 + t;
    if (i >= N) return;
    int s = 0;
#pragma unroll
    for (int b = 0; b < HB; ++b) s += partials[(size_t)b * N + i];
    doutv[i] = s > 0 ? 1.0f / sqrtf((float)s) : 0.0f;
}

// ---------------- binB3': per-bucket offsets; self-computed global prefix ----------------
__global__ __launch_bounds__(128) void k_binB3(const int* __restrict__ counts, const int* __restrict__ tot,
                                               int* __restrict__ base, int* __restrict__ offs,
                                               int nbuck, int E) {
    __shared__ int sm[128];
    __shared__ int pref[128];
    int b = blockIdx.x, t = threadIdx.x;
    int ps = 0;
    for (int j = t; j < b; j += 128) ps += tot[j];
    pref[t] = ps;
    __syncthreads();
#pragma unroll
    for (int o = 64; o >= 1; o >>= 1) {
        if (t < o) pref[t] += pref[t + o];
        __syncthreads();
    }
    int gbase = pref[0];
    int v = counts[(size_t)b * NBLK + t];
    sm[t] = v;
    __syncthreads();
    for (int o = 1; o < 128; o <<= 1) {
        int u = (t >= o) ? sm[t - o] : 0;
        __syncthreads();
        sm[t] += u;
        __syncthreads();
    }
    offs[(size_t)b * NBLK + t] = gbase + sm[t] - v;
    if (t == 127) {
        base[b] = gbase;
        if (b == nbuck - 1) base[nbuck] = E;
    }
}

// ---------------- binC: scatter edges into dst-bucket order ----------------
__global__ __launch_bounds__(256) void k_binC(const int* __restrict__ src, const int* __restrict__ dst,
                                              const int* __restrict__ offs, uint2* __restrict__ binned,
                                              int nbuck, int E) {
    __shared__ int cur[1024];
    for (int i = threadIdx.x; i < nbuck; i += 256) cur[i] = offs[(size_t)i * NBLK + blockIdx.x];
    __syncthreads();
    int per = (E + NBLK - 1) / NBLK;
    int e0 = blockIdx.x * per, e1 = min(e0 + per, E);
    for (int e = e0 + threadIdx.x; e < e1; e += 256) {
        int d = dst[e];
        int p = atomicAdd(&cur[d >> 6], 1);
        binned[p] = make_uint2((unsigned)src[e], (unsigned)d);
    }
}

// ---------------- per-bucket CSR build ----------------
__global__ __launch_bounds__(256) void k_csr(const uint2* __restrict__ binned, const int* __restrict__ base,
                                             int* __restrict__ row_ptr, int* __restrict__ csr_src, int N) {
    __shared__ int hcnt[BROWS], ccur[BROWS];
    int b = blockIdx.x, t = threadIdx.x;
    int e0 = base[b], e1 = base[b + 1];
    if (t < BROWS) hcnt[t] = 0;
    __syncthreads();
    for (int e = e0 + t; e < e1; e += 256)
        atomicAdd(&hcnt[binned[e].y & (BROWS - 1)], 1);
    __syncthreads();
    if (t < BROWS) {
        int acc = 0;
        for (int r = 0; r < t; ++r) acc += hcnt[r];
        ccur[t] = acc;
        int gw = b * BROWS + t;
        if (gw <= N) row_ptr[gw] = e0 + acc;
    }
    __syncthreads();
    for (int e = e0 + t; e < e1; e += 256) {
        uint2 ed = binned[e];
        int p = atomicAdd(&ccur[ed.y & (BROWS - 1)], 1);
        csr_src[e0 + p] = (int)ed.x;
    }
}

// ---------------- MFMA GEMM with pre-packed bf16 weights ----------------
// OUT: 0 = f32 linear, 1 = bf16 linear, 2 = bf16 column-planes [4][n][32]
template <int EPI, int OUT, int DOUT>
__global__ __launch_bounds__(256) void k_gemm_mfma(const unsigned short* __restrict__ A,
                                                   const unsigned short* __restrict__ Wp,
                                                   const float* __restrict__ bias,
                                                   const float* __restrict__ dscale,
                                                   void* __restrict__ Cout, int n) {
    __shared__ uint4 BtV[2176];
    unsigned short* Bt = (unsigned short*)BtV;
    int tid = threadIdx.x;
    const uint4* Wv = (const uint4*)Wp;
    for (int i = tid; i < 2176; i += 256) BtV[i] = Wv[i];
    __syncthreads();

    int wid = tid >> 6, lane = tid & 63;
    int q = lane >> 4, m = lane & 15;
    int r0 = blockIdx.x * 128 + wid * 32;

    f32x4 acc[2][8];
#pragma unroll
    for (int i = 0; i < 2; ++i)
#pragma unroll
        for (int j = 0; j < 8; ++j) acc[i][j] = (f32x4){0.f, 0.f, 0.f, 0.f};

#pragma unroll
    for (int ks = 0; ks < 4; ++ks) {
        int k0 = ks * 32 + q * 8;
        short8 a[2];
#pragma unroll
        for (int i = 0; i < 2; ++i) {
            int row = r0 + i * 16 + m;
            if (row > n - 1) row = n - 1;
            a[i] = *(const short8*)(A + (size_t)row * 128 + k0);
        }
        short8 b[8];
#pragma unroll
        for (int j = 0; j < 8; ++j)
            b[j] = *(const short8*)(&Bt[(j * 16 + m) * 136 + k0]);
#pragma unroll
        for (int i = 0; i < 2; ++i)
#pragma unroll
            for (int j = 0; j < 8; ++j)
                acc[i][j] = __builtin_amdgcn_mfma_f32_16x16x32_bf16(a[i], b[j], acc[i][j], 0, 0, 0);
    }

    float bv[8];
    if (EPI >= 1) {
#pragma unroll
        for (int j = 0; j < 8; ++j) bv[j] = bias[j * 16 + m];
    }

#pragma unroll
    for (int i = 0; i < 2; ++i) {
#pragma unroll
        for (int r = 0; r < 4; ++r) {
            int row = r0 + i * 16 + q * 4 + r;
            if (row < n) {
                float ds = DOUT ? dscale[row] : 1.0f;
#pragma unroll
                for (int j = 0; j < 8; ++j) {
                    float v = acc[i][j][r];
                    if (DOUT) v *= ds;
                    if (EPI >= 1) v += bv[j];
                    if (EPI == 2) v = fmaxf(v, 0.0f);
                    if (OUT == 2) {
                        // col = j*16+m; slice = j>>1; within = (j&1)*16 + m
                        ((unsigned short*)Cout)[((size_t)(j >> 1) * n + row) * 32 + (j & 1) * 16 + m] = f2bf(v);
                    } else if (OUT == 1) {
                        ((unsigned short*)Cout)[(size_t)row * 128 + j * 16 + m] = f2bf(v);
                    } else {
                        ((float*)Cout)[(size_t)row * 128 + j * 16 + m] = v;
                    }
                }
            }
        }
    }
}

// ---------------- XCD-sliced aggregation: slice = (blockIdx&7)>>1 (L2-resident 3.2MB plane) ----------------
// wave = one (row, slice): gathers 64B/edge (8 lanes x 8B, 8 edges parallel);
// emits raw x = agg*din + cb (bf16 plane) + per-slice (sum, sumsq) partials.
__global__ __launch_bounds__(256) void k_agg_slice(const unsigned short* __restrict__ Hp,
                                                   const int* __restrict__ row_ptr,
                                                   const int* __restrict__ csr_src,
                                                   const float* __restrict__ cb,
                                                   unsigned short* __restrict__ xp,
                                                   float* __restrict__ part, int n) {
    int bid = blockIdx.x;
    int s = (bid & 7) >> 1;                       // slice (2 XCDs per slice)
    int idx = (bid >> 3) * 2 + (bid & 1);         // per-slice block index
    int wid = threadIdx.x >> 6, lane = threadIdx.x & 63;
    int row = idx * 4 + wid;
    if (row >= n) return;
    int beg = row_ptr[row], end = row_ptr[row + 1];
    int cnt = end - beg;
    const uint2* P = (const uint2*)(Hp + (size_t)s * n * 32);  // plane row = 8 uint2
    int egrp = lane >> 3, dl = lane & 7;
    float a0 = 0.f, a1 = 0.f, a2 = 0.f, a3 = 0.f;
    for (int c0 = beg; c0 < end; c0 += 64) {
        int m = end - c0;
        if (m > 64) m = 64;
        int myidx = (lane < m) ? __builtin_nontemporal_load(csr_src + c0 + lane) : 0;
        for (int k = 0; k < m; k += 16) {
            int e0 = k + egrp, e1 = k + 8 + egrp;
            int s0 = __shfl(myidx, e0 < m ? e0 : 0, 64);
            int s1 = __shfl(myidx, e1 < m ? e1 : 0, 64);
            uint2 v0 = P[(size_t)s0 * 8 + dl];
            uint2 v1 = P[(size_t)s1 * 8 + dl];
            if (e0 < m) { a0 += bflo(v0.x); a1 += bfhi(v0.x); a2 += bflo(v0.y); a3 += bfhi(v0.y); }
            if (e1 < m) { a0 += bflo(v1.x); a1 += bfhi(v1.x); a2 += bflo(v1.y); a3 += bfhi(v1.y); }
        }
    }
    // reduce over the 8 edge-groups (stride-8 lanes share dl)
#pragma unroll
    for (int o = 8; o < 64; o <<= 1) {
        a0 += __shfl_xor(a0, o, 64);
        a1 += __shfl_xor(a1, o, 64);
        a2 += __shfl_xor(a2, o, 64);
        a3 += __shfl_xor(a3, o, 64);
    }
    float sc = cnt > 0 ? 1.0f / sqrtf((float)cnt) : 0.0f;
    float4 cbv = *(const float4*)(cb + s * 32 + dl * 4);
    float x0 = a0 * sc + cbv.x;
    float x1 = a1 * sc + cbv.y;
    float x2 = a2 * sc + cbv.z;
    float x3 = a3 * sc + cbv.w;
    float p = x0 + x1 + x2 + x3;
    float qq = x0 * x0 + x1 * x1 + x2 * x2 + x3 * x3;
#pragma unroll
    for (int o = 1; o < 8; o <<= 1) {
        p += __shfl_xor(p, o, 64);
        qq += __shfl_xor(qq, o, 64);
    }
    if (egrp == 0) {
        unsigned long long pk = (unsigned long long)pack2bf(x0, x1) |
                                ((unsigned long long)pack2bf(x2, x3) << 32);
        __builtin_nontemporal_store(pk, (unsigned long long*)xp + ((size_t)s * n + row) * 8 + dl);
        if (dl == 0) {
            float2 pq = make_float2(p, qq);
            __builtin_nontemporal_store(*(const double*)&pq,
                                        (double*)part + (size_t)row * 4 + s);
        }
    }
}

// ---------------- LN apply: combine slice partials, normalize, (+relu) ----------------
// MODE 1: out_bf = bf16(relu(LN(x)));  MODE 0: out_f32 = LN(x) AND out_bf = bf16(z)
template <int MODE>
__global__ __launch_bounds__(256) void k_ln_apply(const unsigned short* __restrict__ xp,
                                                  const float* __restrict__ part,
                                                  const float* __restrict__ g, const float* __restrict__ bt,
                                                  float* __restrict__ out_f32,
                                                  unsigned short* __restrict__ out_bf, int n) {
    int row = (blockIdx.x * 256 + threadIdx.x) >> 6;
    int lane = threadIdx.x & 63;
    if (row >= n) return;
    float4 pa = *(const float4*)(part + (size_t)row * 8);
    float4 pb = *(const float4*)(part + (size_t)row * 8 + 4);
    float sum = pa.x + pa.z + pb.x + pb.z;
    float sq  = pa.y + pa.w + pb.y + pb.w;
    float mu = sum * (1.0f / 128.0f);
    float var = sq * (1.0f / 128.0f) - mu * mu;
    float inv = 1.0f / sqrtf(var + LN_EPS);
    int s = lane >> 4, w = lane & 15;             // dims 2*lane, 2*lane+1
    unsigned int v = ((const unsigned int*)xp)[((size_t)s * n + row) * 16 + w];
    float x0 = bflo(v), x1 = bfhi(v);
    int d0 = lane * 2;
    float2 gv = *(const float2*)(g + d0);
    float2 bv = *(const float2*)(bt + d0);
    float y0 = (x0 - mu) * inv * gv.x + bv.x;
    float y1 = (x1 - mu) * inv * gv.y + bv.y;
    if (MODE == 1) {
        y0 = fmaxf(y0, 0.0f);
        y1 = fmaxf(y1, 0.0f);
    } else {
        *(float2*)(out_f32 + (size_t)row * 128 + d0) = make_float2(y0, y1);
    }
    ((unsigned int*)out_bf)[(size_t)row * 64 + lane] = pack2bf(y0, y1);
}

// ---------------- fused decoder + classifier tail ----------------
__global__ __launch_bounds__(256) void k_dec(const unsigned short* __restrict__ A,
                                             const unsigned short* __restrict__ Wp1, const float* __restrict__ bias1,
                                             const unsigned short* __restrict__ Wp2, const float* __restrict__ bias2,
                                             float* __restrict__ Cout,
                                             const float* __restrict__ cW, const float* __restrict__ cbias,
                                             float* __restrict__ logits,
                                             int n, int C, int gb) {
    __shared__ uint4 W1V[2176];
    __shared__ uint4 W2V[2176];
    int tid = threadIdx.x;
    if ((int)blockIdx.x >= gb) {
        int gpos = ((int)blockIdx.x - gb) * 256 + tid;
        int row = gpos >> 4, c = gpos & 15;
        if (row >= n || c >= C) return;
        const unsigned int* zr = (const unsigned int*)(A + (size_t)row * 128);
        float acc = cbias[c];
#pragma unroll 8
        for (int kk = 0; kk < 64; ++kk) {
            unsigned int v = zr[kk];
            acc = fmaf(bflo(v), cW[(2 * kk) * C + c], acc);
            acc = fmaf(bfhi(v), cW[(2 * kk + 1) * C + c], acc);
        }
        logits[(size_t)row * C + c] = acc;
        return;
    }
    const uint4* w1 = (const uint4*)Wp1;
    const uint4* w2 = (const uint4*)Wp2;
    for (int i = tid; i < 2176; i += 256) { W1V[i] = w1[i]; W2V[i] = w2[i]; }
    __syncthreads();
    unsigned short* W1s = (unsigned short*)W1V;
    unsigned short* W2s = (unsigned short*)W2V;

    int wid = tid >> 6, lane = tid & 63;
    int q = lane >> 4, m = lane & 15;
    int r0 = blockIdx.x * 128 + wid * 32;

    f32x4 acc[2][8];
#pragma unroll
    for (int i = 0; i < 2; ++i)
#pragma unroll
        for (int j = 0; j < 8; ++j) acc[i][j] = (f32x4){0.f, 0.f, 0.f, 0.f};
#pragma unroll
    for (int ks = 0; ks < 4; ++ks) {
        int k0 = ks * 32 + q * 8;
        short8 a[2];
#pragma unroll
        for (int i = 0; i < 2; ++i) {
            int row = r0 + i * 16 + m;
            if (row > n - 1) row = n - 1;
            a[i] = *(const short8*)(A + (size_t)row * 128 + k0);
        }
        short8 b[8];
#pragma unroll
        for (int j = 0; j < 8; ++j)
            b[j] = *(const short8*)(&W1s[(j * 16 + m) * 136 + k0]);
#pragma unroll
        for (int i = 0; i < 2; ++i)
#pragma unroll
            for (int j = 0; j < 8; ++j)
                acc[i][j] = __builtin_amdgcn_mfma_f32_16x16x32_bf16(a[i], b[j], acc[i][j], 0, 0, 0);
    }
    float bv[8];
#pragma unroll
    for (int j = 0; j < 8; ++j) bv[j] = bias1[j * 16 + m];

    __syncthreads();
    unsigned short* T = W1s;
#pragma unroll
    for (int i = 0; i < 2; ++i)
#pragma unroll
        for (int r = 0; r < 4; ++r) {
            int lrow = wid * 32 + i * 16 + q * 4 + r;
#pragma unroll
            for (int j = 0; j < 8; ++j) {
                float v = acc[i][j][r] + bv[j];
                T[lrow * 136 + j * 16 + m] = f2bf(fmaxf(v, 0.0f));
            }
        }
    __syncthreads();

#pragma unroll
    for (int i = 0; i < 2; ++i)
#pragma unroll
        for (int j = 0; j < 8; ++j) acc[i][j] = (f32x4){0.f, 0.f, 0.f, 0.f};
#pragma unroll
    for (int ks = 0; ks < 4; ++ks) {
        int k0 = ks * 32 + q * 8;
        short8 a[2];
#pragma unroll
        for (int i = 0; i < 2; ++i)
            a[i] = *(const short8*)(&T[(wid * 32 + i * 16 + m) * 136 + k0]);
        short8 b[8];
#pragma unroll
        for (int j = 0; j < 8; ++j)
            b[j] = *(const short8*)(&W2s[(j * 16 + m) * 136 + k0]);
#pragma unroll
        for (int i = 0; i < 2; ++i)
#pragma unroll
            for (int j = 0; j < 8; ++j)
                acc[i][j] = __builtin_amdgcn_mfma_f32_16x16x32_bf16(a[i], b[j], acc[i][j], 0, 0, 0);
    }
#pragma unroll
    for (int j = 0; j < 8; ++j) bv[j] = bias2[j * 16 + m];
#pragma unroll
    for (int i = 0; i < 2; ++i)
#pragma unroll
        for (int r = 0; r < 4; ++r) {
            int row = r0 + i * 16 + q * 4 + r;
            if (row < n) {
#pragma unroll
                for (int j = 0; j < 8; ++j)
                    Cout[(size_t)row * 128 + j * 16 + m] = acc[i][j][r] + bv[j];
            }
        }
}

extern "C" void kernel_launch(void* const* d_in, const int* in_sizes, int n_in,
                              void* d_out, int out_size, void* d_ws, size_t ws_size,
                              hipStream_t stream) {
    const float* feat  = (const float*)d_in[0];
    const float* noise = (const float*)d_in[1];
    const int*   nmask = (const int*)d_in[2];
    const int*   src   = (const int*)d_in[3];
    const int*   dst   = (const int*)d_in[4];
    const float* token = (const float*)d_in[5];
    const float* W0    = (const float*)d_in[6];
    const float* b0    = (const float*)d_in[7];
    const float* ln0g  = (const float*)d_in[8];
    const float* ln0b  = (const float*)d_in[9];
    const float* W1    = (const float*)d_in[10];
    const float* b1    = (const float*)d_in[11];
    const float* ln1g  = (const float*)d_in[12];
    const float* ln1b  = (const float*)d_in[13];
    const float* dW1   = (const float*)d_in[14];
    const float* db1   = (const float*)d_in[15];
    const float* dW2   = (const float*)d_in[16];
    const float* db2   = (const float*)d_in[17];
    const float* cW    = (const float*)d_in[18];
    const float* cbias = (const float*)d_in[19];

    const int N = in_sizes[0] / 128;
    const int E = in_sizes[3];
    const int C = in_sizes[19];
    const size_t ND = (size_t)N * 128;
    const int NBUCK = (N + BROWS - 1) / BROWS;

    float* out       = (float*)d_out;
    float* out_recon = out;
    float* out_feat  = out + ND;
    float* out_mask  = out + 2 * ND;
    float* out_z     = out + 2 * ND + N;
    float* out_log   = out + 3 * ND + N;

    char* w = (char*)d_ws;
    unsigned short* bufX = (unsigned short*)w; w += ND * 2;   // bf16 linear ping
    unsigned short* bufH = (unsigned short*)w; w += ND * 2;   // bf16 column-planes (gemm out)
    unsigned short* xq   = (unsigned short*)w; w += ND * 2;   // raw-x planes (agg out)
    unsigned short* zbf  = (unsigned short*)w; w += ND * 2;   // bf16 z
    unsigned short* wpack = (unsigned short*)w; w += (size_t)4 * WPSTRIDE * 2;
    float* doutv   = (float*)w; w += (size_t)N * 4;
    float* part    = (float*)w; w += (size_t)N * 8 * 4;       // [N][4] (sum, sumsq) f32 pairs
    int* row_ptr   = (int*)w;   w += (size_t)(N + 4) * 4;
    int* csr_src   = (int*)w;   w += (size_t)E * 4;
    int* scratch   = (int*)w;

    int* partials = scratch;
    uint2* binned = (uint2*)scratch;                          // overlays partials (dead after mid1)
    int* counts = scratch + (size_t)HB * N;
    int* tot    = counts + (size_t)NBUCK * NBLK;
    int* base   = tot + NBUCK;
    int* offs   = base + NBUCK + 2;

    // 1) mega-front
    int prep_blocks = (N * 32 + 255) / 256;
    k_front<<<256 + NBLK + 256 + prep_blocks, 256, 0, stream>>>(
        src, partials, dst, counts, W0, W1, dW1, dW2, wpack,
        feat, noise, nmask, token, bufX, out_feat, out_mask, NBUCK, E, N, N);

    // 2-5) graph build
    int nr = (N + 127) / 128;
    k_mid1<<<NBUCK + nr, 128, 0, stream>>>(counts, tot, partials, doutv, NBUCK, N);
    k_binB3<<<NBUCK, 128, 0, stream>>>(counts, tot, base, offs, NBUCK, E);
    k_binC<<<NBLK, 256, 0, stream>>>(src, dst, offs, binned, NBUCK, E);
    k_csr<<<NBUCK, 256, 0, stream>>>(binned, base, row_ptr, csr_src, N);

    int gb = (N + 127) / 128;
    int rb = (N * 64 + 255) / 256;
    int ab = (((N + 3) / 4 + 1) / 2) * 8;   // agg_slice grid (multiple of 8)

    // 6-8) layer 0: gemm -> sliced agg -> LN+relu
    k_gemm_mfma<0, 2, 1><<<gb, 256, 0, stream>>>(bufX, wpack + 0 * WPSTRIDE, nullptr, doutv, bufH, N);
    k_agg_slice<<<ab, 256, 0, stream>>>(bufH, row_ptr, csr_src, b0, xq, part, N);
    k_ln_apply<1><<<rb, 256, 0, stream>>>(xq, part, ln0g, ln0b, nullptr, bufX, N);

    // 9-11) layer 1 -> z
    k_gemm_mfma<0, 2, 1><<<gb, 256, 0, stream>>>(bufX, wpack + 1 * WPSTRIDE, nullptr, doutv, bufH, N);
    k_agg_slice<<<ab, 256, 0, stream>>>(bufH, row_ptr, csr_src, b1, xq, part, N);
    k_ln_apply<0><<<rb, 256, 0, stream>>>(xq, part, ln1g, ln1b, out_z, zbf, N);

    // 12) fused decoder + classifier
    int cls_blocks = (N * 16 + 255) / 256;
    k_dec<<<gb + cls_blocks, 256, 0, stream>>>(zbf, wpack + 2 * WPSTRIDE, db1, wpack + 3 * WPSTRIDE, db2,
                                               out_recon, cW, cbias, out_log, N, C, gb);
}

// Round 15
// 188.092 us; speedup vs baseline: 1.6019x; 1.6019x over previous
//
#include <hip/hip_runtime.h>
#include <hip/hip_bf16.h>

#define LN_EPS 1e-5f
#define HB 64          // histogram edge-chunks (power of 2)
#define HSEG 12800     // histogram LDS segment (51.2 KB)
#define NBLK 128       // binning blocks
#define BROWS 64       // rows per dst bucket
#define WPSTRIDE 17408 // 128*136 shorts per packed weight

typedef __attribute__((ext_vector_type(8))) short short8;
typedef __attribute__((ext_vector_type(4))) float f32x4;

// ---- bf16 helpers (bit-level, RNE) ----
__device__ __forceinline__ unsigned short f2bf(float f) {
    unsigned int u = __float_as_uint(f);
    u += 0x7fffu + ((u >> 16) & 1u);
    return (unsigned short)(u >> 16);
}
__device__ __forceinline__ unsigned int pack2bf(float a, float b) {
    return (unsigned int)f2bf(a) | ((unsigned int)f2bf(b) << 16);
}
__device__ __forceinline__ float bflo(unsigned int v) { return __uint_as_float(v << 16); }
__device__ __forceinline__ float bfhi(unsigned int v) { return __uint_as_float(v & 0xffff0000u); }

// ---------------- mega-front: hist + binA + weight-pack + prep (one launch) ----------------
__global__ __launch_bounds__(256) void k_front(const int* __restrict__ src, int* __restrict__ partials,
                                               const int* __restrict__ dst, int* __restrict__ counts,
                                               const float* __restrict__ Wa, const float* __restrict__ Wb,
                                               const float* __restrict__ Wc, const float* __restrict__ Wd,
                                               unsigned short* __restrict__ wpack,
                                               const float* __restrict__ feat, const float* __restrict__ noise,
                                               const int* __restrict__ mask, const float* __restrict__ token,
                                               unsigned short* __restrict__ xs, float* __restrict__ feat_out,
                                               float* __restrict__ mask_out,
                                               int nbuck, int E, int n, int N) {
    __shared__ int h[HSEG];
    int bid = blockIdx.x;
    int tid = threadIdx.x;
    if (bid < 256) {
        int chunk = bid & (HB - 1);
        int seg = bid >> 6;
        int lo = seg * HSEG;
        int len = N - lo;
        if (len > HSEG) len = HSEG;
        if (len <= 0) return;
        for (int i = tid; i < len; i += 256) h[i] = 0;
        __syncthreads();
        int per = (E + HB - 1) / HB;
        int e0 = chunk * per, e1 = min(e0 + per, E);
        for (int e = e0 + tid; e < e1; e += 256) {
            int s = src[e] - lo;
            if ((unsigned)s < (unsigned)len) atomicAdd(&h[s], 1);
        }
        __syncthreads();
        for (int i = tid; i < len; i += 256)
            partials[(size_t)chunk * N + lo + i] = h[i];
        return;
    }
    bid -= 256;
    if (bid < NBLK) {
        for (int i = tid; i < nbuck; i += 256) h[i] = 0;
        __syncthreads();
        int per = (E + NBLK - 1) / NBLK;
        int e0 = bid * per, e1 = min(e0 + per, E);
        for (int e = e0 + tid; e < e1; e += 256) atomicAdd(&h[dst[e] >> 6], 1);
        __syncthreads();
        for (int i = tid; i < nbuck; i += 256) counts[(size_t)i * NBLK + bid] = h[i];
        return;
    }
    bid -= NBLK;
    if (bid < 256) {
        int idx = bid * 256 + tid;
        int wsel = idx >> 14;
        int within = idx & 16383;
        const float* W = wsel == 0 ? Wa : wsel == 1 ? Wb : wsel == 2 ? Wc : Wd;
        int c = within >> 7, kk = within & 127;
        wpack[(size_t)wsel * WPSTRIDE + c * 136 + kk] = f2bf(W[kk * 128 + c]);
        return;
    }
    bid -= 256;
    int i = bid * 256 + tid;
    int total = n * 32;
    if (i >= total) return;
    int row = i >> 5, q = i & 31;
    float4 f = ((const float4*)feat)[i];
    float4 nz = ((const float4*)noise)[i];
    bool m = mask[row] != 0;
    float4 b = f;
    if (m) b = ((const float4*)token)[q];
    uint2 p;
    p.x = pack2bf(b.x + 0.1f * nz.x, b.y + 0.1f * nz.y);
    p.y = pack2bf(b.z + 0.1f * nz.z, b.w + 0.1f * nz.w);
    ((uint2*)xs)[i] = p;
    ((float4*)feat_out)[i] = f;
    if (q == 0) mask_out[row] = m ? 1.0f : 0.0f;
}

// ---------------- mid1: binB1 bucket totals + hist reduce ----------------
__global__ __launch_bounds__(128) void k_mid1(const int* __restrict__ counts, int* __restrict__ tot,
                                              const int* __restrict__ partials, float* __restrict__ doutv,
                                              int nbuck, int N) {
    int t = threadIdx.x;
    int bid = blockIdx.x;
    if (bid < nbuck) {
        __shared__ int sm[128];
        sm[t] = counts[(size_t)bid * NBLK + t];
        __syncthreads();
#pragma unroll
        for (int o = 64; o >= 1; o >>= 1) {
            if (t < o) sm[t] += sm[t + o];
            __syncthreads();
        }
        if (t == 0) tot[bid] = sm[0];
        return;
    }
    int i = (bid - nbuck) * 128 + t;
    if (i >= N) return;
    int s = 0;
#pragma unroll
    for (int b = 0; b < HB; ++b) s += partials[(size_t)b * N + i];
    doutv[i] = s > 0 ? 1.0f / sqrtf((float)s) : 0.0f;
}

// ---------------- binB3': per-bucket offsets; self-computed global prefix ----------------
__global__ __launch_bounds__(128) void k_binB3(const int* __restrict__ counts, const int* __restrict__ tot,
                                               int* __restrict__ base, int* __restrict__ offs,
                                               int nbuck, int E) {
    __shared__ int sm[128];
    __shared__ int pref[128];
    int b = blockIdx.x, t = threadIdx.x;
    int ps = 0;
    for (int j = t; j < b; j += 128) ps += tot[j];
    pref[t] = ps;
    __syncthreads();
#pragma unroll
    for (int o = 64; o >= 1; o >>= 1) {
        if (t < o) pref[t] += pref[t + o];
        __syncthreads();
    }
    int gbase = pref[0];
    int v = counts[(size_t)b * NBLK + t];
    sm[t] = v;
    __syncthreads();
    for (int o = 1; o < 128; o <<= 1) {
        int u = (t >= o) ? sm[t - o] : 0;
        __syncthreads();
        sm[t] += u;
        __syncthreads();
    }
    offs[(size_t)b * NBLK + t] = gbase + sm[t] - v;
    if (t == 127) {
        base[b] = gbase;
        if (b == nbuck - 1) base[nbuck] = E;
    }
}

// ---------------- binC: scatter edges into dst-bucket order ----------------
__global__ __launch_bounds__(256) void k_binC(const int* __restrict__ src, const int* __restrict__ dst,
                                              const int* __restrict__ offs, uint2* __restrict__ binned,
                                              int nbuck, int E) {
    __shared__ int cur[1024];
    for (int i = threadIdx.x; i < nbuck; i += 256) cur[i] = offs[(size_t)i * NBLK + blockIdx.x];
    __syncthreads();
    int per = (E + NBLK - 1) / NBLK;
    int e0 = blockIdx.x * per, e1 = min(e0 + per, E);
    for (int e = e0 + threadIdx.x; e < e1; e += 256) {
        int d = dst[e];
        int p = atomicAdd(&cur[d >> 6], 1);
        binned[p] = make_uint2((unsigned)src[e], (unsigned)d);
    }
}

// ---------------- per-bucket CSR build ----------------
__global__ __launch_bounds__(256) void k_csr(const uint2* __restrict__ binned, const int* __restrict__ base,
                                             int* __restrict__ row_ptr, int* __restrict__ csr_src, int N) {
    __shared__ int hcnt[BROWS], ccur[BROWS];
    int b = blockIdx.x, t = threadIdx.x;
    int e0 = base[b], e1 = base[b + 1];
    if (t < BROWS) hcnt[t] = 0;
    __syncthreads();
    for (int e = e0 + t; e < e1; e += 256)
        atomicAdd(&hcnt[binned[e].y & (BROWS - 1)], 1);
    __syncthreads();
    if (t < BROWS) {
        int acc = 0;
        for (int r = 0; r < t; ++r) acc += hcnt[r];
        ccur[t] = acc;
        int gw = b * BROWS + t;
        if (gw <= N) row_ptr[gw] = e0 + acc;
    }
    __syncthreads();
    for (int e = e0 + t; e < e1; e += 256) {
        uint2 ed = binned[e];
        int p = atomicAdd(&ccur[ed.y & (BROWS - 1)], 1);
        csr_src[e0 + p] = (int)ed.x;
    }
}

// ---------------- MFMA GEMM with pre-packed bf16 weights ----------------
// C[n,128] = A_bf16[n,128] @ Wp (*dout[row])(+bias)(+relu)
template <int EPI, int OUT_BF16, int DOUT>
__global__ __launch_bounds__(256) void k_gemm_mfma(const unsigned short* __restrict__ A,
                                                   const unsigned short* __restrict__ Wp,
                                                   const float* __restrict__ bias,
                                                   const float* __restrict__ dscale,
                                                   void* __restrict__ Cout, int n) {
    __shared__ uint4 BtV[2176];  // 128*136 bf16 = 34816 B
    unsigned short* Bt = (unsigned short*)BtV;
    int tid = threadIdx.x;
    const uint4* Wv = (const uint4*)Wp;
    for (int i = tid; i < 2176; i += 256) BtV[i] = Wv[i];
    __syncthreads();

    int wid = tid >> 6, lane = tid & 63;
    int q = lane >> 4, m = lane & 15;
    int r0 = blockIdx.x * 128 + wid * 32;

    f32x4 acc[2][8];
#pragma unroll
    for (int i = 0; i < 2; ++i)
#pragma unroll
        for (int j = 0; j < 8; ++j) acc[i][j] = (f32x4){0.f, 0.f, 0.f, 0.f};

#pragma unroll
    for (int ks = 0; ks < 4; ++ks) {
        int k0 = ks * 32 + q * 8;
        short8 a[2];
#pragma unroll
        for (int i = 0; i < 2; ++i) {
            int row = r0 + i * 16 + m;
            if (row > n - 1) row = n - 1;  // clamp; discarded at store
            a[i] = *(const short8*)(A + (size_t)row * 128 + k0);
        }
        short8 b[8];
#pragma unroll
        for (int j = 0; j < 8; ++j)
            b[j] = *(const short8*)(&Bt[(j * 16 + m) * 136 + k0]);
#pragma unroll
        for (int i = 0; i < 2; ++i)
#pragma unroll
            for (int j = 0; j < 8; ++j)
                acc[i][j] = __builtin_amdgcn_mfma_f32_16x16x32_bf16(a[i], b[j], acc[i][j], 0, 0, 0);
    }

    float bv[8];
    if (EPI >= 1) {
#pragma unroll
        for (int j = 0; j < 8; ++j) bv[j] = bias[j * 16 + m];
    }

#pragma unroll
    for (int i = 0; i < 2; ++i) {
#pragma unroll
        for (int r = 0; r < 4; ++r) {
            int row = r0 + i * 16 + q * 4 + r;
            if (row < n) {
                float ds = DOUT ? dscale[row] : 1.0f;
#pragma unroll
                for (int j = 0; j < 8; ++j) {
                    float v = acc[i][j][r];
                    if (DOUT) v *= ds;
                    if (EPI >= 1) v += bv[j];
                    if (EPI == 2) v = fmaxf(v, 0.0f);
                    if (OUT_BF16)
                        ((unsigned short*)Cout)[(size_t)row * 128 + j * 16 + m] = f2bf(v);
                    else
                        ((float*)Cout)[(size_t)row * 128 + j * 16 + m] = v;
                }
            }
        }
    }
}

// ---------------- fused decoder + classifier tail: both read zbf ----------------
__global__ __launch_bounds__(256) void k_dec(const unsigned short* __restrict__ A,
                                             const unsigned short* __restrict__ Wp1, const float* __restrict__ bias1,
                                             const unsigned short* __restrict__ Wp2, const float* __restrict__ bias2,
                                             float* __restrict__ Cout,
                                             const float* __restrict__ cW, const float* __restrict__ cbias,
                                             float* __restrict__ logits,
                                             int n, int C, int gb) {
    __shared__ uint4 W1V[2176];   // dW1; reused as T tile after phase 1
    __shared__ uint4 W2V[2176];   // dW2
    int tid = threadIdx.x;
    if ((int)blockIdx.x >= gb) {
        // ---- classifier tail blocks ----
        int gpos = ((int)blockIdx.x - gb) * 256 + tid;
        int row = gpos >> 4, c = gpos & 15;
        if (row >= n || c >= C) return;
        const unsigned int* zr = (const unsigned int*)(A + (size_t)row * 128);
        float acc = cbias[c];
#pragma unroll 8
        for (int kk = 0; kk < 64; ++kk) {
            unsigned int v = zr[kk];
            acc = fmaf(bflo(v), cW[(2 * kk) * C + c], acc);
            acc = fmaf(bfhi(v), cW[(2 * kk + 1) * C + c], acc);
        }
        logits[(size_t)row * C + c] = acc;
        return;
    }
    const uint4* w1 = (const uint4*)Wp1;
    const uint4* w2 = (const uint4*)Wp2;
    for (int i = tid; i < 2176; i += 256) { W1V[i] = w1[i]; W2V[i] = w2[i]; }
    __syncthreads();
    unsigned short* W1s = (unsigned short*)W1V;
    unsigned short* W2s = (unsigned short*)W2V;

    int wid = tid >> 6, lane = tid & 63;
    int q = lane >> 4, m = lane & 15;
    int r0 = blockIdx.x * 128 + wid * 32;

    // phase 1: acc = z @ dW1
    f32x4 acc[2][8];
#pragma unroll
    for (int i = 0; i < 2; ++i)
#pragma unroll
        for (int j = 0; j < 8; ++j) acc[i][j] = (f32x4){0.f, 0.f, 0.f, 0.f};
#pragma unroll
    for (int ks = 0; ks < 4; ++ks) {
        int k0 = ks * 32 + q * 8;
        short8 a[2];
#pragma unroll
        for (int i = 0; i < 2; ++i) {
            int row = r0 + i * 16 + m;
            if (row > n - 1) row = n - 1;
            a[i] = *(const short8*)(A + (size_t)row * 128 + k0);
        }
        short8 b[8];
#pragma unroll
        for (int j = 0; j < 8; ++j)
            b[j] = *(const short8*)(&W1s[(j * 16 + m) * 136 + k0]);
#pragma unroll
        for (int i = 0; i < 2; ++i)
#pragma unroll
            for (int j = 0; j < 8; ++j)
                acc[i][j] = __builtin_amdgcn_mfma_f32_16x16x32_bf16(a[i], b[j], acc[i][j], 0, 0, 0);
    }
    float bv[8];
#pragma unroll
    for (int j = 0; j < 8; ++j) bv[j] = bias1[j * 16 + m];

    __syncthreads();   // all waves done reading W1s
    unsigned short* T = W1s;   // reuse as 128x136 bf16 tile
#pragma unroll
    for (int i = 0; i < 2; ++i)
#pragma unroll
        for (int r = 0; r < 4; ++r) {
            int lrow = wid * 32 + i * 16 + q * 4 + r;
#pragma unroll
            for (int j = 0; j < 8; ++j) {
                float v = acc[i][j][r] + bv[j];
                T[lrow * 136 + j * 16 + m] = f2bf(fmaxf(v, 0.0f));
            }
        }
    __syncthreads();

    // phase 2: out = T @ dW2 + db2
#pragma unroll
    for (int i = 0; i < 2; ++i)
#pragma unroll
        for (int j = 0; j < 8; ++j) acc[i][j] = (f32x4){0.f, 0.f, 0.f, 0.f};
#pragma unroll
    for (int ks = 0; ks < 4; ++ks) {
        int k0 = ks * 32 + q * 8;
        short8 a[2];
#pragma unroll
        for (int i = 0; i < 2; ++i)
            a[i] = *(const short8*)(&T[(wid * 32 + i * 16 + m) * 136 + k0]);
        short8 b[8];
#pragma unroll
        for (int j = 0; j < 8; ++j)
            b[j] = *(const short8*)(&W2s[(j * 16 + m) * 136 + k0]);
#pragma unroll
        for (int i = 0; i < 2; ++i)
#pragma unroll
            for (int j = 0; j < 8; ++j)
                acc[i][j] = __builtin_amdgcn_mfma_f32_16x16x32_bf16(a[i], b[j], acc[i][j], 0, 0, 0);
    }
#pragma unroll
    for (int j = 0; j < 8; ++j) bv[j] = bias2[j * 16 + m];
#pragma unroll
    for (int i = 0; i < 2; ++i)
#pragma unroll
        for (int r = 0; r < 4; ++r) {
            int row = r0 + i * 16 + q * 4 + r;
            if (row < n) {
#pragma unroll
                for (int j = 0; j < 8; ++j)
                    Cout[(size_t)row * 128 + j * 16 + m] = acc[i][j][r] + bv[j];
            }
        }
}

// ---------------- fused CSR agg (half-wave edge pairs, uint2 gather) + LN (+relu) ----------------
// MODE 1: out_bf = bf16( relu(LN(agg*din+cb)) )
// MODE 0: out_f32 = LN(agg*din+cb)  AND  out_bf = bf16(z)
template <int MODE>
__global__ __launch_bounds__(256) void k_agg_ln(const unsigned short* __restrict__ H,
                                                const int* __restrict__ row_ptr,
                                                const int* __restrict__ csr_src,
                                                const float* __restrict__ cb, const float* __restrict__ g,
                                                const float* __restrict__ bt,
                                                float* __restrict__ out_f32, unsigned short* __restrict__ out_bf,
                                                int n) {
    int gw = (blockIdx.x * blockDim.x + threadIdx.x) >> 6;
    int lane = threadIdx.x & 63;
    if (gw >= n) return;
    int beg = row_ptr[gw], end = row_ptr[gw + 1];
    int cnt = end - beg;
    const uint2* H2 = (const uint2*)H;   // one row = 32 uint2 (256 B)
    int half = lane >> 5;                // 0: even edges, 1: odd edges
    int hl = lane & 31;                  // covers dims [4*hl, 4*hl+4)
    float a0 = 0.f, a1 = 0.f, a2 = 0.f, a3 = 0.f;
    for (int c0 = beg; c0 < end; c0 += 64) {
        int m = end - c0;
        if (m > 64) m = 64;
        int myidx = (lane < m) ? csr_src[c0 + lane] : 0;  // coalesced index load
        int k = 0;
        for (; k + 15 < m; k += 16) {    // 8 loads in flight = 16 edges
            uint2 v[8];
#pragma unroll
            for (int p = 0; p < 8; ++p) {
                int s = __shfl(myidx, k + 2 * p + half);
                v[p] = H2[(size_t)s * 32 + hl];
            }
#pragma unroll
            for (int p = 0; p < 8; ++p) {
                a0 += bflo(v[p].x); a1 += bfhi(v[p].x);
                a2 += bflo(v[p].y); a3 += bfhi(v[p].y);
            }
        }
        for (; k + 7 < m; k += 8) {      // 4 loads in flight = 8 edges
            uint2 v[4];
#pragma unroll
            for (int p = 0; p < 4; ++p) {
                int s = __shfl(myidx, k + 2 * p + half);
                v[p] = H2[(size_t)s * 32 + hl];
            }
#pragma unroll
            for (int p = 0; p < 4; ++p) {
                a0 += bflo(v[p].x); a1 += bfhi(v[p].x);
                a2 += bflo(v[p].y); a3 += bfhi(v[p].y);
            }
        }
        for (; k < m; k += 2) {          // tail pairs
            int e = k + half;
            int s = __shfl(myidx, (e < m) ? e : k);
            uint2 vv = H2[(size_t)s * 32 + hl];
            if (e < m) {
                a0 += bflo(vv.x); a1 += bfhi(vv.x);
                a2 += bflo(vv.y); a3 += bfhi(vv.y);
            }
        }
    }
    // merge halves: partner lane (^32) holds the other edge-parity partial for SAME dims
    a0 += __shfl_xor(a0, 32, 64);
    a1 += __shfl_xor(a1, 32, 64);
    a2 += __shfl_xor(a2, 32, 64);
    a3 += __shfl_xor(a3, 32, 64);

    int d0 = hl * 4;
    float sc = cnt > 0 ? 1.0f / sqrtf((float)cnt) : 0.0f;
    float4 cbv = *(const float4*)(cb + d0);
    float x0 = a0 * sc + cbv.x;
    float x1 = a1 * sc + cbv.y;
    float x2 = a2 * sc + cbv.z;
    float x3 = a3 * sc + cbv.w;

    float s = x0 + x1 + x2 + x3;
#pragma unroll
    for (int mm = 16; mm >= 1; mm >>= 1) s += __shfl_xor(s, mm, 64);
    float mu = s * (1.0f / 128.0f);
    float dx0 = x0 - mu, dx1 = x1 - mu, dx2 = x2 - mu, dx3 = x3 - mu;
    float v = dx0 * dx0 + dx1 * dx1 + dx2 * dx2 + dx3 * dx3;
#pragma unroll
    for (int mm = 16; mm >= 1; mm >>= 1) v += __shfl_xor(v, mm, 64);
    float inv = 1.0f / sqrtf(v * (1.0f / 128.0f) + LN_EPS);
    float4 gv = *(const float4*)(g + d0);
    float4 bvv = *(const float4*)(bt + d0);
    float y0 = dx0 * inv * gv.x + bvv.x;
    float y1 = dx1 * inv * gv.y + bvv.y;
    float y2 = dx2 * inv * gv.z + bvv.z;
    float y3 = dx3 * inv * gv.w + bvv.w;
    if (MODE == 1) {
        y0 = fmaxf(y0, 0.0f); y1 = fmaxf(y1, 0.0f);
        y2 = fmaxf(y2, 0.0f); y3 = fmaxf(y3, 0.0f);
    }
    if (half == 0) {
        if (MODE == 0) {
            float4 z4 = make_float4(y0, y1, y2, y3);
            *(float4*)(out_f32 + (size_t)gw * 128 + d0) = z4;
        }
        uint2 pk;
        pk.x = pack2bf(y0, y1);
        pk.y = pack2bf(y2, y3);
        ((uint2*)out_bf)[(size_t)gw * 32 + hl] = pk;
    }
}

extern "C" void kernel_launch(void* const* d_in, const int* in_sizes, int n_in,
                              void* d_out, int out_size, void* d_ws, size_t ws_size,
                              hipStream_t stream) {
    const float* feat  = (const float*)d_in[0];
    const float* noise = (const float*)d_in[1];
    const int*   nmask = (const int*)d_in[2];
    const int*   src   = (const int*)d_in[3];
    const int*   dst   = (const int*)d_in[4];
    const float* token = (const float*)d_in[5];
    const float* W0    = (const float*)d_in[6];
    const float* b0    = (const float*)d_in[7];
    const float* ln0g  = (const float*)d_in[8];
    const float* ln0b  = (const float*)d_in[9];
    const float* W1    = (const float*)d_in[10];
    const float* b1    = (const float*)d_in[11];
    const float* ln1g  = (const float*)d_in[12];
    const float* ln1b  = (const float*)d_in[13];
    const float* dW1   = (const float*)d_in[14];
    const float* db1   = (const float*)d_in[15];
    const float* dW2   = (const float*)d_in[16];
    const float* db2   = (const float*)d_in[17];
    const float* cW    = (const float*)d_in[18];
    const float* cbias = (const float*)d_in[19];

    const int N = in_sizes[0] / 128;
    const int E = in_sizes[3];
    const int C = in_sizes[19];
    const size_t ND = (size_t)N * 128;
    const int NBUCK = (N + BROWS - 1) / BROWS;  // 782 for N=50000 (<= 1024)

    float* out       = (float*)d_out;
    float* out_recon = out;
    float* out_feat  = out + ND;
    float* out_mask  = out + 2 * ND;
    float* out_z     = out + 2 * ND + N;
    float* out_log   = out + 3 * ND + N;

    char* w = (char*)d_ws;
    unsigned short* bufX = (unsigned short*)w; w += ND * 2;   // bf16 ping
    unsigned short* bufH = (unsigned short*)w; w += ND * 2;   // bf16 pong
    unsigned short* zbf  = (unsigned short*)w; w += ND * 2;   // bf16 z
    unsigned short* wpack = (unsigned short*)w; w += (size_t)4 * WPSTRIDE * 2;  // packed weights
    float* doutv   = (float*)w; w += (size_t)N * 4;
    int* row_ptr   = (int*)w;   w += (size_t)(N + 4) * 4;
    int* csr_src   = (int*)w;   w += (size_t)E * 4;
    int* scratch   = (int*)w;   // union region

    // phase-1 view: partials (HB*N ints); binned overlays it after k_mid1 consumed it
    int* partials = scratch;
    uint2* binned = (uint2*)scratch;                          // E entries (dead partials region)
    int* counts = scratch + (size_t)HB * N;                   // NBUCK*NBLK (disjoint from partials)
    int* tot    = counts + (size_t)NBUCK * NBLK;              // NBUCK
    int* base   = tot + NBUCK;                                // NBUCK+1
    int* offs   = base + NBUCK + 2;                           // NBUCK*NBLK

    // 1) mega-front: hist + binA + pack + prep (one launch; components run concurrently)
    int prep_blocks = (N * 32 + 255) / 256;
    k_front<<<256 + NBLK + 256 + prep_blocks, 256, 0, stream>>>(
        src, partials, dst, counts, W0, W1, dW1, dW2, wpack,
        feat, noise, nmask, token, bufX, out_feat, out_mask, NBUCK, E, N, N);

    // 2) mid1: binB1 totals + hist reduce (block-parallel, one launch)
    int nr = (N + 127) / 128;
    k_mid1<<<NBUCK + nr, 128, 0, stream>>>(counts, tot, partials, doutv, NBUCK, N);

    // 3) binB3': per-bucket offsets (self-computed global prefix) -> offs, base
    k_binB3<<<NBUCK, 128, 0, stream>>>(counts, tot, base, offs, NBUCK, E);

    // 4) scatter into dst-bucket order;  5) per-bucket CSR finalize
    k_binC<<<NBLK, 256, 0, stream>>>(src, dst, offs, binned, NBUCK, E);
    k_csr<<<NBUCK, 256, 0, stream>>>(binned, base, row_ptr, csr_src, N);

    int gb = (N + 127) / 128;
    int rb = (N * 64 + 255) / 256;

    // 6-7) layer 0
    k_gemm_mfma<0, 1, 1><<<gb, 256, 0, stream>>>(bufX, wpack + 0 * WPSTRIDE, nullptr, doutv, bufH, N);
    k_agg_ln<1><<<rb, 256, 0, stream>>>(bufH, row_ptr, csr_src, b0, ln0g, ln0b, nullptr, bufX, N);

    // 8-9) layer 1 -> z
    k_gemm_mfma<0, 1, 1><<<gb, 256, 0, stream>>>(bufX, wpack + 1 * WPSTRIDE, nullptr, doutv, bufH, N);
    k_agg_ln<0><<<rb, 256, 0, stream>>>(bufH, row_ptr, csr_src, b1, ln1g, ln1b, out_z, zbf, N);

    // 10) fused decoder + classifier (both read zbf)
    int cls_blocks = (N * 16 + 255) / 256;
    k_dec<<<gb + cls_blocks, 256, 0, stream>>>(zbf, wpack + 2 * WPSTRIDE, db1, wpack + 3 * WPSTRIDE, db2,
                                               out_recon, cW, cbias, out_log, N, C, gb);
}